// Round 4
// baseline (597.108 us; speedup 1.0000x reference)
//
#include <hip/hip_runtime.h>
#include <hip/hip_bf16.h>
#include <cstdint>
#include <cstddef>

#define EPS 1e-5f

typedef __attribute__((ext_vector_type(4))) int int32x4;

// ---------------- block reduction helpers (256 threads = 4 waves) ----------------
__device__ __forceinline__ float blk_sum(float v, float* s4) {
    #pragma unroll
    for (int o = 32; o; o >>= 1) v += __shfl_down(v, o, 64);
    if ((threadIdx.x & 63) == 0) s4[threadIdx.x >> 6] = v;
    __syncthreads();
    v = s4[0] + s4[1] + s4[2] + s4[3];
    __syncthreads();
    return v;
}

__device__ __forceinline__ void blk_sum2(float& a, float& b, float* s8) {
    #pragma unroll
    for (int o = 32; o; o >>= 1) {
        a += __shfl_down(a, o, 64);
        b += __shfl_down(b, o, 64);
    }
    if ((threadIdx.x & 63) == 0) {
        s8[threadIdx.x >> 6] = a;
        s8[4 + (threadIdx.x >> 6)] = b;
    }
    __syncthreads();
    a = s8[0] + s8[1] + s8[2] + s8[3];
    b = s8[4] + s8[5] + s8[6] + s8[7];
    __syncthreads();
}

__device__ __forceinline__ float blk_max(float v, float* s4) {
    #pragma unroll
    for (int o = 32; o; o >>= 1) v = fmaxf(v, __shfl_down(v, o, 64));
    if ((threadIdx.x & 63) == 0) s4[threadIdx.x >> 6] = v;
    __syncthreads();
    v = fmaxf(fmaxf(s4[0], s4[1]), fmaxf(s4[2], s4[3]));
    __syncthreads();
    return v;
}

__device__ __forceinline__ int pack4(float a, float b, float c, float d, float lo, float hi) {
    int x0 = (int)fminf(fmaxf(a, lo), hi);
    int x1 = (int)fminf(fmaxf(b, lo), hi);
    int x2 = (int)fminf(fmaxf(c, lo), hi);
    int x3 = (int)fminf(fmaxf(d, lo), hi);
    return (x0 & 255) | ((x1 & 255) << 8) | ((x2 & 255) << 16) | ((x3 & 255) << 24);
}

__device__ __forceinline__ float bflo(unsigned u) { return __uint_as_float(u << 16); }
__device__ __forceinline__ float bfhi(unsigned u) { return __uint_as_float(u & 0xffff0000u); }

// ---------------- fused absmean over all 4 weights (1 launch, loop-free blocks) --------
// Each block covers 1024 float4 = 16 KB; each thread 4 consecutive float4 (4 loads in
// flight). Grid: W0 1024 | W1 4096 | W2 4096 | W3 2000 = 11216 blocks.
__global__ __launch_bounds__(256) void absmean_all_kernel(
    const float* __restrict__ W0, const float* __restrict__ W1,
    const float* __restrict__ W2, const float* __restrict__ W3,
    float* __restrict__ sums) {
    __shared__ float s4[4];
    const float* w; int sidx; unsigned rel;
    unsigned bx = blockIdx.x;
    if (bx < 1024)      { w = W0; sidx = 0; rel = bx; }
    else if (bx < 5120) { w = W1; sidx = 1; rel = bx - 1024; }
    else if (bx < 9216) { w = W2; sidx = 2; rel = bx - 5120; }
    else                { w = W3; sidx = 3; rel = bx - 9216; }
    const float4* p = (const float4*)w + (size_t)rel * 1024 + threadIdx.x * 4;
    float4 v0 = p[0], v1 = p[1], v2 = p[2], v3 = p[3];
    float s = fabsf(v0.x) + fabsf(v0.y) + fabsf(v0.z) + fabsf(v0.w)
            + fabsf(v1.x) + fabsf(v1.y) + fabsf(v1.z) + fabsf(v1.w)
            + fabsf(v2.x) + fabsf(v2.y) + fabsf(v2.z) + fabsf(v2.w)
            + fabsf(v3.x) + fabsf(v3.y) + fabsf(v3.z) + fabsf(v3.w);
    s = blk_sum(s, s4);
    if (threadIdx.x == 0) atomicAdd(&sums[sidx], s);
}

// ---------------- fused ternary quantization for all 4 weights + W3 pad ----------------
// Same block layout; W3 padded to 2048 blocks (rel>=2000 -> all-zero, no loads).
// Grid: 1024 | 4096 | 4096 | 2048 = 11264 blocks. One int4 store per thread.
__global__ __launch_bounds__(256) void wquant_all_kernel(
    const float* __restrict__ W0, const float* __restrict__ W1,
    const float* __restrict__ W2, const float* __restrict__ W3,
    int* __restrict__ q0, int* __restrict__ q1, int* __restrict__ q2, int* __restrict__ q3,
    const float* __restrict__ sums) {
    const float* w; int* q; int sidx; unsigned rel; float invN; bool pad = false;
    unsigned bx = blockIdx.x;
    if (bx < 1024)      { w = W0; q = q0; sidx = 0; rel = bx;        invN = 1.f / 4194304.f; }
    else if (bx < 5120) { w = W1; q = q1; sidx = 1; rel = bx - 1024; invN = 1.f / 16777216.f; }
    else if (bx < 9216) { w = W2; q = q2; sidx = 2; rel = bx - 5120; invN = 1.f / 16777216.f; }
    else                { w = W3; q = q3; sidx = 3; rel = bx - 9216; invN = 1.f / 8192000.f;
                          pad = (rel >= 2000); }
    int4 o = {0, 0, 0, 0};
    if (!pad) {
        float mean = fmaxf(sums[sidx] * invN, EPS);
        float scale = 1.f / mean;
        const float4* p = (const float4*)w + (size_t)rel * 1024 + threadIdx.x * 4;
        float4 v0 = p[0], v1 = p[1], v2 = p[2], v3 = p[3];
        o.x = pack4(rintf(v0.x * scale), rintf(v0.y * scale), rintf(v0.z * scale), rintf(v0.w * scale), -1.f, 1.f);
        o.y = pack4(rintf(v1.x * scale), rintf(v1.y * scale), rintf(v1.z * scale), rintf(v1.w * scale), -1.f, 1.f);
        o.z = pack4(rintf(v2.x * scale), rintf(v2.y * scale), rintf(v2.z * scale), rintf(v2.w * scale), -1.f, 1.f);
        o.w = pack4(rintf(v3.x * scale), rintf(v3.y * scale), rintf(v3.z * scale), rintf(v3.w * scale), -1.f, 1.f);
    }
    ((int4*)q)[(size_t)rel * 256 + threadIdx.x] = o;
}

// ---------------- input activation quantization (D = 1024) ----------------
__global__ __launch_bounds__(256) void actquant_kernel(const float* __restrict__ x,
                                                       int* __restrict__ q,
                                                       float* __restrict__ inv_s) {
    __shared__ float s4[4];
    int row = blockIdx.x;
    const float4* xr = (const float4*)(x + (size_t)row * 1024);
    float4 v = xr[threadIdx.x];
    float m = fmaxf(fmaxf(fabsf(v.x), fabsf(v.y)), fmaxf(fabsf(v.z), fabsf(v.w)));
    m = blk_max(m, s4);
    m = fmaxf(m, EPS);
    float scale = 127.f / m;
    if (threadIdx.x == 0) inv_s[row] = m / 127.f;
    q[(size_t)row * 256 + threadIdx.x] =
        pack4(rintf(v.x * scale), rintf(v.y * scale),
              rintf(v.z * scale), rintf(v.w * scale), -128.f, 127.f);
}

// ---------------- fused LayerNorm + SiLU + act quant, bf16 input (H = 4096) ------------
__global__ __launch_bounds__(256) void ln_silu_quant_kernel(const ushort* __restrict__ h,
                                                            const float* __restrict__ g,
                                                            const float* __restrict__ b,
                                                            int* __restrict__ q,
                                                            float* __restrict__ inv_s) {
    __shared__ float s8[8];
    int row = blockIdx.x;
    int t = threadIdx.x;
    const uint4* hr = (const uint4*)(h + (size_t)row * 4096);
    uint4 p0 = hr[t * 2], p1 = hr[t * 2 + 1];  // 16 bf16 elems per thread
    float f[16];
    f[0] = bflo(p0.x); f[1] = bfhi(p0.x); f[2] = bflo(p0.y); f[3] = bfhi(p0.y);
    f[4] = bflo(p0.z); f[5] = bfhi(p0.z); f[6] = bflo(p0.w); f[7] = bfhi(p0.w);
    f[8] = bflo(p1.x); f[9] = bfhi(p1.x); f[10] = bflo(p1.y); f[11] = bfhi(p1.y);
    f[12] = bflo(p1.z); f[13] = bfhi(p1.z); f[14] = bflo(p1.w); f[15] = bfhi(p1.w);
    float sum = 0.f, sq = 0.f;
    #pragma unroll
    for (int i = 0; i < 16; i++) { sum += f[i]; sq += f[i] * f[i]; }
    blk_sum2(sum, sq, s8);
    float mu = sum * (1.f / 4096.f);
    float var = sq * (1.f / 4096.f) - mu * mu;
    float rs = rsqrtf(var + EPS);
    const float4* g4 = (const float4*)g;
    const float4* b4 = (const float4*)b;
    float amax = 0.f;
    #pragma unroll
    for (int i = 0; i < 4; i++) {
        float4 gg = g4[t * 4 + i];
        float4 bb = b4[t * 4 + i];
        float y0 = (f[i * 4 + 0] - mu) * rs * gg.x + bb.x;
        float y1 = (f[i * 4 + 1] - mu) * rs * gg.y + bb.y;
        float y2 = (f[i * 4 + 2] - mu) * rs * gg.z + bb.z;
        float y3 = (f[i * 4 + 3] - mu) * rs * gg.w + bb.w;
        f[i * 4 + 0] = y0 / (1.f + expf(-y0));
        f[i * 4 + 1] = y1 / (1.f + expf(-y1));
        f[i * 4 + 2] = y2 / (1.f + expf(-y2));
        f[i * 4 + 3] = y3 / (1.f + expf(-y3));
    }
    #pragma unroll
    for (int i = 0; i < 16; i++) amax = fmaxf(amax, fabsf(f[i]));
    amax = blk_max(amax, s8);
    amax = fmaxf(amax, EPS);
    float scale = 127.f / amax;
    if (t == 0) inv_s[row] = amax / 127.f;
    int4 o;
    o.x = pack4(rintf(f[0] * scale), rintf(f[1] * scale), rintf(f[2] * scale), rintf(f[3] * scale), -128.f, 127.f);
    o.y = pack4(rintf(f[4] * scale), rintf(f[5] * scale), rintf(f[6] * scale), rintf(f[7] * scale), -128.f, 127.f);
    o.z = pack4(rintf(f[8] * scale), rintf(f[9] * scale), rintf(f[10] * scale), rintf(f[11] * scale), -128.f, 127.f);
    o.w = pack4(rintf(f[12] * scale), rintf(f[13] * scale), rintf(f[14] * scale), rintf(f[15] * scale), -128.f, 127.f);
    ((int4*)((char*)q + (size_t)row * 4096))[t] = o;
}

// ---------------- i8 MFMA GEMM: C[b,o] = sum_k A[b,k]*B[o,k] ----------------
// 128x128 tile, BK=128 (32 KB LDS), XOR-swizzled rows, 16x16x64 MFMA,
// 4 waves each computing a 64x64 quadrant (4x4 of 16x16x64).
// Swizzle: element (row, c) stored at LDS col c ^ (16*(row&7)); implemented by
// permuting the per-lane GLOBAL source address (LDS side must stay lane*16).
__device__ __forceinline__ void load_lds16(const void* g, void* l) {
    __builtin_amdgcn_global_load_lds((__attribute__((address_space(1))) void*)(g),
                                     (__attribute__((address_space(3))) void*)(l), 16, 0, 0);
}

template <int MODE>  // 0: write bf16 h[gr*4096+gc]; 1: final sigmoid epilogue into d_out
__global__ __launch_bounds__(256, 2) void gemm_i8_kernel(
    const char* __restrict__ A, const char* __restrict__ B,
    const float* __restrict__ inv_s, const float* __restrict__ wsum, float invWN,
    int K, void* __restrict__ outp) {
    __shared__ __align__(16) char lA[128 * 128];
    __shared__ __align__(16) char lB[128 * 128];
    const int t = threadIdx.x;
    const int lane = t & 63;
    const int wave = t >> 6;
    const int bm = blockIdx.y * 128, bn = blockIdx.x * 128;
    const int wr = (wave >> 1) * 64, wc = (wave & 1) * 64;

    int32x4 acc[4][4] = {};

    // staging: LDS linear slot li = j*4096 + t*16 -> row = j*32 + (t>>3),
    // storage col = (t&7)*16; global col = storage col ^ 16*(row&7) (row&7 == r0&7)
    const int r0 = t >> 3;
    const int c0 = (t & 7) * 16;
    const int gcol = c0 ^ (16 * (r0 & 7));
    const char* gA = A + (size_t)(bm + r0) * K + gcol;
    const char* gB = B + (size_t)(bn + r0) * K + gcol;
    char* sA = lA + t * 16;
    char* sB = lB + t * 16;

    const int fr = lane & 15;
    const int fq = lane >> 4;
    const int swz = 16 * (fr & 7);  // (wr + mt*16 + fr) & 7 == fr & 7

    for (int k0 = 0; k0 < K; k0 += 128) {
        #pragma unroll
        for (int j = 0; j < 4; j++)
            load_lds16(gA + (size_t)(j * 32) * K + k0, sA + j * 4096);
        #pragma unroll
        for (int j = 0; j < 4; j++)
            load_lds16(gB + (size_t)(j * 32) * K + k0, sB + j * 4096);
        __syncthreads();

        #pragma unroll
        for (int ks = 0; ks < 2; ks++) {
            const int col = (ks * 64 + fq * 16) ^ swz;
            int32x4 af[4], bf[4];
            #pragma unroll
            for (int mt = 0; mt < 4; mt++)
                af[mt] = *(const int32x4*)(lA + (wr + mt * 16 + fr) * 128 + col);
            #pragma unroll
            for (int nt = 0; nt < 4; nt++)
                bf[nt] = *(const int32x4*)(lB + (wc + nt * 16 + fr) * 128 + col);
            #pragma unroll
            for (int mt = 0; mt < 4; mt++) {
                #pragma unroll
                for (int nt = 0; nt < 4; nt++) {
                    acc[mt][nt] = __builtin_amdgcn_mfma_i32_16x16x64_i8(af[mt], bf[nt],
                                                                        acc[mt][nt], 0, 0, 0);
                }
            }
        }
        __syncthreads();
    }

    // epilogue: C/D layout col = lane&15, row = (lane>>4)*4 + reg
    const float wmean = fmaxf(wsum[0] * invWN, EPS);
    #pragma unroll
    for (int mt = 0; mt < 4; mt++) {
        #pragma unroll
        for (int rg = 0; rg < 4; rg++) {
            int gr = bm + wr + mt * 16 + fq * 4 + rg;
            float rowscale = inv_s[gr] * wmean;
            #pragma unroll
            for (int nt = 0; nt < 4; nt++) {
                int gc = bn + wc + nt * 16 + fr;
                float v = (float)acc[mt][nt][rg] * rowscale;
                if (MODE == 0) {
                    ((__hip_bfloat16*)outp)[(size_t)gr * 4096 + gc] = __float2bfloat16(v);
                } else {
                    if (gc < 2000) {
                        float sg = 1.f / (1.f + expf(-v));
                        float* out = (float*)outp;
                        if (gc < 1000)
                            out[(size_t)gr * 1000 + gc] = sg * 999.f + 1.f;
                        else
                            out[(size_t)4096 * 1000 + (size_t)gr * 1000 + (gc - 1000)] =
                                sg * 100.f;
                    }
                }
            }
        }
    }
}

// ---------------- host launcher ----------------
extern "C" void kernel_launch(void* const* d_in, const int* in_sizes, int n_in,
                              void* d_out, int out_size, void* d_ws, size_t ws_size,
                              hipStream_t stream) {
    const float* x  = (const float*)d_in[0];
    const float* W0 = (const float*)d_in[1];
    const float* W1 = (const float*)d_in[2];
    const float* W2 = (const float*)d_in[3];
    const float* W3 = (const float*)d_in[4];
    const float* g0 = (const float*)d_in[5];
    const float* b0 = (const float*)d_in[6];
    const float* g1 = (const float*)d_in[7];
    const float* b1 = (const float*)d_in[8];
    const float* g2 = (const float*)d_in[9];
    const float* b2 = (const float*)d_in[10];
    float* out = (float*)d_out;

    char* ws = (char*)d_ws;
    size_t off = 0;
    auto alloc = [&](size_t bytes) -> char* {
        char* p = ws + off;
        off = (off + bytes + 255) & ~(size_t)255;
        return p;
    };
    float* sums = (float*)alloc(4 * sizeof(float));
    float* inv0 = (float*)alloc(4096 * 4);
    float* inv1 = (float*)alloc(4096 * 4);
    float* inv2 = (float*)alloc(4096 * 4);
    float* inv3 = (float*)alloc(4096 * 4);
    char* wq0 = alloc(4096ll * 1024);
    char* wq1 = alloc(4096ll * 4096);
    char* wq2 = alloc(4096ll * 4096);
    char* wq3 = alloc(2048ll * 4096);   // padded to 2048 rows
    char* a0  = alloc(4096ll * 1024);
    char* a1  = alloc(4096ll * 4096);
    char* a2  = alloc(4096ll * 4096);
    char* h   = alloc(4096ll * 4096 * 2);  // bf16 intermediate
    char* a3 = a1;  // a1 dead after GEMM1; safe sequential reuse

    hipMemsetAsync(sums, 0, 4 * sizeof(float), stream);

    absmean_all_kernel<<<11216, 256, 0, stream>>>(W0, W1, W2, W3, sums);
    actquant_kernel<<<4096, 256, 0, stream>>>(x, (int*)a0, inv0);
    wquant_all_kernel<<<11264, 256, 0, stream>>>(W0, W1, W2, W3, (int*)wq0, (int*)wq1,
                                                 (int*)wq2, (int*)wq3, sums);

    gemm_i8_kernel<0><<<dim3(32, 32), 256, 0, stream>>>(a0, wq0, inv0, sums + 0,
                                                        1.f / 4194304.f, 1024, h);
    ln_silu_quant_kernel<<<4096, 256, 0, stream>>>((const ushort*)h, g0, b0, (int*)a1, inv1);

    gemm_i8_kernel<0><<<dim3(32, 32), 256, 0, stream>>>(a1, wq1, inv1, sums + 1,
                                                        1.f / 16777216.f, 4096, h);
    ln_silu_quant_kernel<<<4096, 256, 0, stream>>>((const ushort*)h, g1, b1, (int*)a2, inv2);

    gemm_i8_kernel<0><<<dim3(32, 32), 256, 0, stream>>>(a2, wq2, inv2, sums + 2,
                                                        1.f / 16777216.f, 4096, h);
    ln_silu_quant_kernel<<<4096, 256, 0, stream>>>((const ushort*)h, g2, b2, (int*)a3, inv3);

    gemm_i8_kernel<1><<<dim3(16, 32), 256, 0, stream>>>(a3, wq3, inv3, sums + 3,
                                                        1.f / 8192000.f, 4096, out);
}

// Round 5
// 520.140 us; speedup vs baseline: 1.1480x; 1.1480x over previous
//
#include <hip/hip_runtime.h>
#include <hip/hip_bf16.h>
#include <cstdint>
#include <cstddef>

#define EPS 1e-5f

typedef __attribute__((ext_vector_type(4))) int int32x4;

// ---------------- block reduction helpers (256 threads = 4 waves) ----------------
__device__ __forceinline__ float blk_sum(float v, float* s4) {
    #pragma unroll
    for (int o = 32; o; o >>= 1) v += __shfl_down(v, o, 64);
    if ((threadIdx.x & 63) == 0) s4[threadIdx.x >> 6] = v;
    __syncthreads();
    v = s4[0] + s4[1] + s4[2] + s4[3];
    __syncthreads();
    return v;
}

__device__ __forceinline__ void blk_sum2(float& a, float& b, float* s8) {
    #pragma unroll
    for (int o = 32; o; o >>= 1) {
        a += __shfl_down(a, o, 64);
        b += __shfl_down(b, o, 64);
    }
    if ((threadIdx.x & 63) == 0) {
        s8[threadIdx.x >> 6] = a;
        s8[4 + (threadIdx.x >> 6)] = b;
    }
    __syncthreads();
    a = s8[0] + s8[1] + s8[2] + s8[3];
    b = s8[4] + s8[5] + s8[6] + s8[7];
    __syncthreads();
}

__device__ __forceinline__ float blk_max(float v, float* s4) {
    #pragma unroll
    for (int o = 32; o; o >>= 1) v = fmaxf(v, __shfl_down(v, o, 64));
    if ((threadIdx.x & 63) == 0) s4[threadIdx.x >> 6] = v;
    __syncthreads();
    v = fmaxf(fmaxf(s4[0], s4[1]), fmaxf(s4[2], s4[3]));
    __syncthreads();
    return v;
}

__device__ __forceinline__ int pack4(float a, float b, float c, float d, float lo, float hi) {
    int x0 = (int)fminf(fmaxf(a, lo), hi);
    int x1 = (int)fminf(fmaxf(b, lo), hi);
    int x2 = (int)fminf(fmaxf(c, lo), hi);
    int x3 = (int)fminf(fmaxf(d, lo), hi);
    return (x0 & 255) | ((x1 & 255) << 8) | ((x2 & 255) << 16) | ((x3 & 255) << 24);
}

__device__ __forceinline__ float bflo(unsigned u) { return __uint_as_float(u << 16); }
__device__ __forceinline__ float bfhi(unsigned u) { return __uint_as_float(u & 0xffff0000u); }

// ---------------- fused absmean over all 4 weights (1 launch) --------------------------
// Each block covers 1024 float4 = 16 KB; thread t loads float4 at t, t+256, t+512, t+768
// (4 independent, per-instruction wave-contiguous 1 KB). Partials go to 256 spread slots
// (64/weight, 64 B apart) to avoid single-cache-line atomic serialization (R4 lesson).
__global__ __launch_bounds__(256) void absmean_all_kernel(
    const float* __restrict__ W0, const float* __restrict__ W1,
    const float* __restrict__ W2, const float* __restrict__ W3,
    float* __restrict__ part) {
    __shared__ float s4[4];
    const float* w; int sidx; unsigned rel;
    unsigned bx = blockIdx.x;
    if (bx < 1024)      { w = W0; sidx = 0; rel = bx; }
    else if (bx < 5120) { w = W1; sidx = 1; rel = bx - 1024; }
    else if (bx < 9216) { w = W2; sidx = 2; rel = bx - 5120; }
    else                { w = W3; sidx = 3; rel = bx - 9216; }
    const float4* p = (const float4*)w + (size_t)rel * 1024 + threadIdx.x;
    float4 v0 = p[0], v1 = p[256], v2 = p[512], v3 = p[768];
    float s = fabsf(v0.x) + fabsf(v0.y) + fabsf(v0.z) + fabsf(v0.w)
            + fabsf(v1.x) + fabsf(v1.y) + fabsf(v1.z) + fabsf(v1.w)
            + fabsf(v2.x) + fabsf(v2.y) + fabsf(v2.z) + fabsf(v2.w)
            + fabsf(v3.x) + fabsf(v3.y) + fabsf(v3.z) + fabsf(v3.w);
    s = blk_sum(s, s4);
    // slot stride 16 floats = 64 B: each of the 256 slots sits on its own cache line
    if (threadIdx.x == 0) atomicAdd(&part[(sidx * 64 + (rel & 63)) * 16], s);
}

// ---------------- reduce 256 spread slots -> sums[4] (1 block; wave w = weight w) ------
__global__ __launch_bounds__(256) void reduce_sums_kernel(const float* __restrict__ part,
                                                          float* __restrict__ sums) {
    int w = threadIdx.x >> 6, l = threadIdx.x & 63;
    float v = part[(w * 64 + l) * 16];
    #pragma unroll
    for (int o = 32; o; o >>= 1) v += __shfl_down(v, o, 64);
    if (l == 0) sums[w] = v;
}

// ---------------- fused ternary quantization for all 4 weights + W3 pad ----------------
// W3 padded to 2048 blocks (rel>=2000 -> all-zero, no loads). One int4 store per thread.
__global__ __launch_bounds__(256) void wquant_all_kernel(
    const float* __restrict__ W0, const float* __restrict__ W1,
    const float* __restrict__ W2, const float* __restrict__ W3,
    int* __restrict__ q0, int* __restrict__ q1, int* __restrict__ q2, int* __restrict__ q3,
    const float* __restrict__ sums) {
    const float* w; int* q; int sidx; unsigned rel; float invN; bool pad = false;
    unsigned bx = blockIdx.x;
    if (bx < 1024)      { w = W0; q = q0; sidx = 0; rel = bx;        invN = 1.f / 4194304.f; }
    else if (bx < 5120) { w = W1; q = q1; sidx = 1; rel = bx - 1024; invN = 1.f / 16777216.f; }
    else if (bx < 9216) { w = W2; q = q2; sidx = 2; rel = bx - 5120; invN = 1.f / 16777216.f; }
    else                { w = W3; q = q3; sidx = 3; rel = bx - 9216; invN = 1.f / 8192000.f;
                          pad = (rel >= 2000); }
    int4 o = {0, 0, 0, 0};
    if (!pad) {
        float mean = fmaxf(sums[sidx] * invN, EPS);
        float scale = 1.f / mean;
        const float4* p = (const float4*)w + (size_t)rel * 1024 + threadIdx.x * 4;
        float4 v0 = p[0], v1 = p[1], v2 = p[2], v3 = p[3];
        o.x = pack4(rintf(v0.x * scale), rintf(v0.y * scale), rintf(v0.z * scale), rintf(v0.w * scale), -1.f, 1.f);
        o.y = pack4(rintf(v1.x * scale), rintf(v1.y * scale), rintf(v1.z * scale), rintf(v1.w * scale), -1.f, 1.f);
        o.z = pack4(rintf(v2.x * scale), rintf(v2.y * scale), rintf(v2.z * scale), rintf(v2.w * scale), -1.f, 1.f);
        o.w = pack4(rintf(v3.x * scale), rintf(v3.y * scale), rintf(v3.z * scale), rintf(v3.w * scale), -1.f, 1.f);
    }
    ((int4*)q)[(size_t)rel * 256 + threadIdx.x] = o;
}

// ---------------- input activation quantization (D = 1024) ----------------
__global__ __launch_bounds__(256) void actquant_kernel(const float* __restrict__ x,
                                                       int* __restrict__ q,
                                                       float* __restrict__ inv_s) {
    __shared__ float s4[4];
    int row = blockIdx.x;
    const float4* xr = (const float4*)(x + (size_t)row * 1024);
    float4 v = xr[threadIdx.x];
    float m = fmaxf(fmaxf(fabsf(v.x), fabsf(v.y)), fmaxf(fabsf(v.z), fabsf(v.w)));
    m = blk_max(m, s4);
    m = fmaxf(m, EPS);
    float scale = 127.f / m;
    if (threadIdx.x == 0) inv_s[row] = m / 127.f;
    q[(size_t)row * 256 + threadIdx.x] =
        pack4(rintf(v.x * scale), rintf(v.y * scale),
              rintf(v.z * scale), rintf(v.w * scale), -128.f, 127.f);
}

// ---------------- fused LayerNorm + SiLU + act quant, bf16 input (H = 4096) ------------
__global__ __launch_bounds__(256) void ln_silu_quant_kernel(const ushort* __restrict__ h,
                                                            const float* __restrict__ g,
                                                            const float* __restrict__ b,
                                                            int* __restrict__ q,
                                                            float* __restrict__ inv_s) {
    __shared__ float s8[8];
    int row = blockIdx.x;
    int t = threadIdx.x;
    const uint4* hr = (const uint4*)(h + (size_t)row * 4096);
    uint4 p0 = hr[t * 2], p1 = hr[t * 2 + 1];  // 16 bf16 elems per thread
    float f[16];
    f[0] = bflo(p0.x); f[1] = bfhi(p0.x); f[2] = bflo(p0.y); f[3] = bfhi(p0.y);
    f[4] = bflo(p0.z); f[5] = bfhi(p0.z); f[6] = bflo(p0.w); f[7] = bfhi(p0.w);
    f[8] = bflo(p1.x); f[9] = bfhi(p1.x); f[10] = bflo(p1.y); f[11] = bfhi(p1.y);
    f[12] = bflo(p1.z); f[13] = bfhi(p1.z); f[14] = bflo(p1.w); f[15] = bfhi(p1.w);
    float sum = 0.f, sq = 0.f;
    #pragma unroll
    for (int i = 0; i < 16; i++) { sum += f[i]; sq += f[i] * f[i]; }
    blk_sum2(sum, sq, s8);
    float mu = sum * (1.f / 4096.f);
    float var = sq * (1.f / 4096.f) - mu * mu;
    float rs = rsqrtf(var + EPS);
    const float4* g4 = (const float4*)g;
    const float4* b4 = (const float4*)b;
    float amax = 0.f;
    #pragma unroll
    for (int i = 0; i < 4; i++) {
        float4 gg = g4[t * 4 + i];
        float4 bb = b4[t * 4 + i];
        float y0 = (f[i * 4 + 0] - mu) * rs * gg.x + bb.x;
        float y1 = (f[i * 4 + 1] - mu) * rs * gg.y + bb.y;
        float y2 = (f[i * 4 + 2] - mu) * rs * gg.z + bb.z;
        float y3 = (f[i * 4 + 3] - mu) * rs * gg.w + bb.w;
        f[i * 4 + 0] = y0 / (1.f + expf(-y0));
        f[i * 4 + 1] = y1 / (1.f + expf(-y1));
        f[i * 4 + 2] = y2 / (1.f + expf(-y2));
        f[i * 4 + 3] = y3 / (1.f + expf(-y3));
    }
    #pragma unroll
    for (int i = 0; i < 16; i++) amax = fmaxf(amax, fabsf(f[i]));
    amax = blk_max(amax, s8);
    amax = fmaxf(amax, EPS);
    float scale = 127.f / amax;
    if (t == 0) inv_s[row] = amax / 127.f;
    int4 o;
    o.x = pack4(rintf(f[0] * scale), rintf(f[1] * scale), rintf(f[2] * scale), rintf(f[3] * scale), -128.f, 127.f);
    o.y = pack4(rintf(f[4] * scale), rintf(f[5] * scale), rintf(f[6] * scale), rintf(f[7] * scale), -128.f, 127.f);
    o.z = pack4(rintf(f[8] * scale), rintf(f[9] * scale), rintf(f[10] * scale), rintf(f[11] * scale), -128.f, 127.f);
    o.w = pack4(rintf(f[12] * scale), rintf(f[13] * scale), rintf(f[14] * scale), rintf(f[15] * scale), -128.f, 127.f);
    ((int4*)((char*)q + (size_t)row * 4096))[t] = o;
}

// ---------------- i8 MFMA GEMM: C[b,o] = sum_k A[b,k]*B[o,k] ----------------
// 128x128 tile, BK=128 (32 KB LDS), XOR-swizzled rows, 16x16x64 MFMA,
// 4 waves each computing a 64x64 quadrant (4x4 of 16x16x64).
__device__ __forceinline__ void load_lds16(const void* g, void* l) {
    __builtin_amdgcn_global_load_lds((__attribute__((address_space(1))) void*)(g),
                                     (__attribute__((address_space(3))) void*)(l), 16, 0, 0);
}

template <int MODE>  // 0: write bf16 h[gr*4096+gc]; 1: final sigmoid epilogue into d_out
__global__ __launch_bounds__(256, 2) void gemm_i8_kernel(
    const char* __restrict__ A, const char* __restrict__ B,
    const float* __restrict__ inv_s, const float* __restrict__ wsum, float invWN,
    int K, void* __restrict__ outp) {
    __shared__ __align__(16) char lA[128 * 128];
    __shared__ __align__(16) char lB[128 * 128];
    const int t = threadIdx.x;
    const int lane = t & 63;
    const int wave = t >> 6;
    const int bm = blockIdx.y * 128, bn = blockIdx.x * 128;
    const int wr = (wave >> 1) * 64, wc = (wave & 1) * 64;

    int32x4 acc[4][4] = {};

    const int r0 = t >> 3;
    const int c0 = (t & 7) * 16;
    const int gcol = c0 ^ (16 * (r0 & 7));
    const char* gA = A + (size_t)(bm + r0) * K + gcol;
    const char* gB = B + (size_t)(bn + r0) * K + gcol;
    char* sA = lA + t * 16;
    char* sB = lB + t * 16;

    const int fr = lane & 15;
    const int fq = lane >> 4;
    const int swz = 16 * (fr & 7);

    for (int k0 = 0; k0 < K; k0 += 128) {
        #pragma unroll
        for (int j = 0; j < 4; j++)
            load_lds16(gA + (size_t)(j * 32) * K + k0, sA + j * 4096);
        #pragma unroll
        for (int j = 0; j < 4; j++)
            load_lds16(gB + (size_t)(j * 32) * K + k0, sB + j * 4096);
        __syncthreads();

        #pragma unroll
        for (int ks = 0; ks < 2; ks++) {
            const int col = (ks * 64 + fq * 16) ^ swz;
            int32x4 af[4], bf[4];
            #pragma unroll
            for (int mt = 0; mt < 4; mt++)
                af[mt] = *(const int32x4*)(lA + (wr + mt * 16 + fr) * 128 + col);
            #pragma unroll
            for (int nt = 0; nt < 4; nt++)
                bf[nt] = *(const int32x4*)(lB + (wc + nt * 16 + fr) * 128 + col);
            #pragma unroll
            for (int mt = 0; mt < 4; mt++) {
                #pragma unroll
                for (int nt = 0; nt < 4; nt++) {
                    acc[mt][nt] = __builtin_amdgcn_mfma_i32_16x16x64_i8(af[mt], bf[nt],
                                                                        acc[mt][nt], 0, 0, 0);
                }
            }
        }
        __syncthreads();
    }

    const float wmean = fmaxf(wsum[0] * invWN, EPS);
    #pragma unroll
    for (int mt = 0; mt < 4; mt++) {
        #pragma unroll
        for (int rg = 0; rg < 4; rg++) {
            int gr = bm + wr + mt * 16 + fq * 4 + rg;
            float rowscale = inv_s[gr] * wmean;
            #pragma unroll
            for (int nt = 0; nt < 4; nt++) {
                int gc = bn + wc + nt * 16 + fr;
                float v = (float)acc[mt][nt][rg] * rowscale;
                if (MODE == 0) {
                    ((__hip_bfloat16*)outp)[(size_t)gr * 4096 + gc] = __float2bfloat16(v);
                } else {
                    if (gc < 2000) {
                        float sg = 1.f / (1.f + expf(-v));
                        float* out = (float*)outp;
                        if (gc < 1000)
                            out[(size_t)gr * 1000 + gc] = sg * 999.f + 1.f;
                        else
                            out[(size_t)4096 * 1000 + (size_t)gr * 1000 + (gc - 1000)] =
                                sg * 100.f;
                    }
                }
            }
        }
    }
}

// ---------------- host launcher ----------------
extern "C" void kernel_launch(void* const* d_in, const int* in_sizes, int n_in,
                              void* d_out, int out_size, void* d_ws, size_t ws_size,
                              hipStream_t stream) {
    const float* x  = (const float*)d_in[0];
    const float* W0 = (const float*)d_in[1];
    const float* W1 = (const float*)d_in[2];
    const float* W2 = (const float*)d_in[3];
    const float* W3 = (const float*)d_in[4];
    const float* g0 = (const float*)d_in[5];
    const float* b0 = (const float*)d_in[6];
    const float* g1 = (const float*)d_in[7];
    const float* b1 = (const float*)d_in[8];
    const float* g2 = (const float*)d_in[9];
    const float* b2 = (const float*)d_in[10];
    float* out = (float*)d_out;

    char* ws = (char*)d_ws;
    size_t off = 0;
    auto alloc = [&](size_t bytes) -> char* {
        char* p = ws + off;
        off = (off + bytes + 255) & ~(size_t)255;
        return p;
    };
    float* part = (float*)alloc(256 * 16 * sizeof(float));  // 256 slots, 64 B apart
    float* sums = (float*)alloc(4 * sizeof(float));
    float* inv0 = (float*)alloc(4096 * 4);
    float* inv1 = (float*)alloc(4096 * 4);
    float* inv2 = (float*)alloc(4096 * 4);
    float* inv3 = (float*)alloc(4096 * 4);
    char* wq0 = alloc(4096ll * 1024);
    char* wq1 = alloc(4096ll * 4096);
    char* wq2 = alloc(4096ll * 4096);
    char* wq3 = alloc(2048ll * 4096);   // padded to 2048 rows
    char* a0  = alloc(4096ll * 1024);
    char* a1  = alloc(4096ll * 4096);
    char* a2  = alloc(4096ll * 4096);
    char* h   = alloc(4096ll * 4096 * 2);  // bf16 intermediate
    char* a3 = a1;  // a1 dead after GEMM1; safe sequential reuse

    hipMemsetAsync(part, 0, 256 * 16 * sizeof(float), stream);

    absmean_all_kernel<<<11216, 256, 0, stream>>>(W0, W1, W2, W3, part);
    reduce_sums_kernel<<<1, 256, 0, stream>>>(part, sums);
    actquant_kernel<<<4096, 256, 0, stream>>>(x, (int*)a0, inv0);
    wquant_all_kernel<<<11264, 256, 0, stream>>>(W0, W1, W2, W3, (int*)wq0, (int*)wq1,
                                                 (int*)wq2, (int*)wq3, sums);

    gemm_i8_kernel<0><<<dim3(32, 32), 256, 0, stream>>>(a0, wq0, inv0, sums + 0,
                                                        1.f / 4194304.f, 1024, h);
    ln_silu_quant_kernel<<<4096, 256, 0, stream>>>((const ushort*)h, g0, b0, (int*)a1, inv1);

    gemm_i8_kernel<0><<<dim3(32, 32), 256, 0, stream>>>(a1, wq1, inv1, sums + 1,
                                                        1.f / 16777216.f, 4096, h);
    ln_silu_quant_kernel<<<4096, 256, 0, stream>>>((const ushort*)h, g1, b1, (int*)a2, inv2);

    gemm_i8_kernel<0><<<dim3(32, 32), 256, 0, stream>>>(a2, wq2, inv2, sums + 2,
                                                        1.f / 16777216.f, 4096, h);
    ln_silu_quant_kernel<<<4096, 256, 0, stream>>>((const ushort*)h, g2, b2, (int*)a3, inv3);

    gemm_i8_kernel<1><<<dim3(16, 32), 256, 0, stream>>>(a3, wq3, inv3, sums + 3,
                                                        1.f / 8192000.f, 4096, out);
}